// Round 3
// baseline (705.233 us; speedup 1.0000x reference)
//
#include <hip/hip_runtime.h>
#include <cstdint>
#include <cstddef>

// Problem constants (fixed by the reference)
#define HIDDEN 2048
#define INTER 5504
#define BS_ROWS 1024   // bsz*seq = 2*512
#define MROWS 4096     // T*bsz*seq
#define BK 64

// Guide-verified MFMA fragment types (compile-verified on gfx950):
typedef short bf16x8 __attribute__((ext_vector_type(8)));   // 8 bf16 in 4 VGPRs
typedef float f32x4 __attribute__((ext_vector_type(4)));

__device__ __forceinline__ unsigned short f2bf(float f) {
  unsigned int u = __float_as_uint(f);
  u += 0x7fffu + ((u >> 16) & 1u);   // round-to-nearest-even
  return (unsigned short)(u >> 16);
}

// fp32 -> bf16 conversion, float4-vectorized (memory-bound)
__global__ void convert_kernel(const float* __restrict__ in,
                               unsigned short* __restrict__ out, int n4) {
  int i = blockIdx.x * blockDim.x + threadIdx.x;
  if (i >= n4) return;
  float4 v = reinterpret_cast<const float4*>(in)[i];
  ushort4 o;
  o.x = f2bf(v.x); o.y = f2bf(v.y); o.z = f2bf(v.z); o.w = f2bf(v.w);
  reinterpret_cast<ushort4*>(out)[i] = o;
}

// async global->LDS, 16B per lane; lds dst is wave-uniform base + lane*16
__device__ __forceinline__ void gload16(const unsigned short* g, unsigned short* lds) {
  __builtin_amdgcn_global_load_lds(
      (const __attribute__((address_space(1))) unsigned int*)g,
      (__attribute__((address_space(3))) unsigned int*)lds, 16, 0, 0);
}

// ---------------------------------------------------------------------------
// GEMM1 (fused): out_g/out_up projections + cumsum/silu/hadamard epilogue.
// Block = 256 threads (4 waves, 2x2). Tile: 128 "rows" x 128 inter-cols.
// Tile row i encodes: t = (i>>4)&3, row-group g = i>>6, j = i&15
//   global m(i) = t*1024 + r0 + g*16 + j
// => MFMA m-fragment index == t, so each thread's acc[m=t][n][reg] holds the
//    4 timesteps of the SAME (row, col) -> elementwise coupling is thread-local.
// ---------------------------------------------------------------------------
__global__ __launch_bounds__(256) void gemm1_fused(
    const unsigned short* __restrict__ xb,   // 4096 x 2048 bf16
    const unsigned short* __restrict__ wg,   // 5504 x 2048 bf16
    const unsigned short* __restrict__ wu,   // 5504 x 2048 bf16
    unsigned short* __restrict__ cb) {       // 4096 x 5504 bf16 (C)
  __shared__ unsigned short As[128 * BK];
  __shared__ unsigned short Bg[128 * BK];
  __shared__ unsigned short Bu[128 * BK];

  const int tid = threadIdx.x;
  const int lane = tid & 63;
  const int wv = tid >> 6;
  const int wr = wv >> 1;   // row-group of wave (0,1)
  const int wc = wv & 1;    // col half (0,1)

  const int r0 = blockIdx.y * 32;    // (b,s)-row base
  const int n0 = blockIdx.x * 128;   // inter col base

  f32x4 accg[4][4], accu[4][4];
#pragma unroll
  for (int m = 0; m < 4; ++m)
#pragma unroll
    for (int n = 0; n < 4; ++n) {
      accg[m][n] = f32x4{0.f, 0.f, 0.f, 0.f};
      accu[m][n] = f32x4{0.f, 0.f, 0.f, 0.f};
    }

  const int s_row = lane >> 3;        // 0..7 row within 8-row chunk
  const int s_col = (lane & 7) * 8;   // 0..56, 8 bf16 = 16B per lane

  for (int k0 = 0; k0 < HIDDEN; k0 += BK) {
#pragma unroll
    for (int c = 0; c < 4; ++c) {
      const int idx = c * 4 + wv;        // chunk 0..15 (wave-uniform)
      const int tr = idx * 8 + s_row;    // tile row 0..127
      const int t = (tr >> 4) & 3;
      const int grow = t * BS_ROWS + r0 + (tr >> 6) * 16 + (tr & 15);
      gload16(xb + (size_t)grow * HIDDEN + k0 + s_col, &As[idx * 512]);
      gload16(wg + (size_t)(n0 + tr) * HIDDEN + k0 + s_col, &Bg[idx * 512]);
      gload16(wu + (size_t)(n0 + tr) * HIDDEN + k0 + s_col, &Bu[idx * 512]);
    }
    __syncthreads();
#pragma unroll
    for (int kk = 0; kk < 2; ++kk) {
      const int ko = kk * 32 + (lane >> 4) * 8;
      bf16x8 af[4], bgf[4], buf[4];
#pragma unroll
      for (int m = 0; m < 4; ++m) {
        const int row = wr * 64 + m * 16 + (lane & 15);
        af[m] = *reinterpret_cast<const bf16x8*>(&As[row * BK + ko]);
      }
#pragma unroll
      for (int n = 0; n < 4; ++n) {
        const int row = wc * 64 + n * 16 + (lane & 15);
        bgf[n] = *reinterpret_cast<const bf16x8*>(&Bg[row * BK + ko]);
        buf[n] = *reinterpret_cast<const bf16x8*>(&Bu[row * BK + ko]);
      }
#pragma unroll
      for (int m = 0; m < 4; ++m)
#pragma unroll
        for (int n = 0; n < 4; ++n) {
          accg[m][n] = __builtin_amdgcn_mfma_f32_16x16x32_bf16(af[m], bgf[n], accg[m][n], 0, 0, 0);
          accu[m][n] = __builtin_amdgcn_mfma_f32_16x16x32_bf16(af[m], buf[n], accu[m][n], 0, 0, 0);
        }
    }
    __syncthreads();
  }

  // Epilogue: X_t = cumsum(g), Y_t = silu(X_t), A_t = Y_t - Y_{t-1},
  // SA = Y_3, SB = sum(u), C_t = 0.5*(A_t*SB + u_t*SA)
  const int cc = lane & 15;            // col within 16x16 frag
  const int jj0 = (lane >> 4) * 4;     // row base within frag
#pragma unroll
  for (int n = 0; n < 4; ++n) {
    const int col = n0 + wc * 64 + n * 16 + cc;
#pragma unroll
    for (int r = 0; r < 4; ++r) {
      const int row_bs = r0 + wr * 16 + jj0 + r;
      const float g0 = accg[0][n][r], g1 = accg[1][n][r];
      const float g2 = accg[2][n][r], g3 = accg[3][n][r];
      const float u0 = accu[0][n][r], u1 = accu[1][n][r];
      const float u2 = accu[2][n][r], u3 = accu[3][n][r];
      float xx = g0;
      const float y0 = xx / (1.f + __expf(-xx));
      xx += g1;
      const float y1 = xx / (1.f + __expf(-xx));
      xx += g2;
      const float y2 = xx / (1.f + __expf(-xx));
      xx += g3;
      const float y3 = xx / (1.f + __expf(-xx));
      const float sa = y3;
      const float sb = u0 + u1 + u2 + u3;
      const size_t base = (size_t)row_bs * INTER + col;
      const size_t ts = (size_t)BS_ROWS * INTER;
      cb[base]          = f2bf(0.5f * (y0 * sb + u0 * sa));
      cb[base + ts]     = f2bf(0.5f * ((y1 - y0) * sb + u1 * sa));
      cb[base + 2 * ts] = f2bf(0.5f * ((y2 - y1) * sb + u2 * sa));
      cb[base + 3 * ts] = f2bf(0.5f * ((y3 - y2) * sb + u3 * sa));
    }
  }
}

// ---------------------------------------------------------------------------
// GEMM2: down = C @ w_down^T.  Standard 128x128 tile, B^T (K-major both sides).
// ---------------------------------------------------------------------------
__global__ __launch_bounds__(256) void gemm2_down(
    const unsigned short* __restrict__ cb,   // 4096 x 5504 bf16
    const unsigned short* __restrict__ wd,   // 2048 x 5504 bf16
    float* __restrict__ out) {               // 4096 x 2048 f32
  __shared__ unsigned short As[128 * BK];
  __shared__ unsigned short Bs[128 * BK];

  const int tid = threadIdx.x;
  const int lane = tid & 63;
  const int wv = tid >> 6;
  const int wr = wv >> 1;
  const int wc = wv & 1;

  const int m0 = blockIdx.y * 128;
  const int n0 = blockIdx.x * 128;

  f32x4 acc[4][4];
#pragma unroll
  for (int m = 0; m < 4; ++m)
#pragma unroll
    for (int n = 0; n < 4; ++n) acc[m][n] = f32x4{0.f, 0.f, 0.f, 0.f};

  const int s_row = lane >> 3;
  const int s_col = (lane & 7) * 8;

  for (int k0 = 0; k0 < INTER; k0 += BK) {  // 86 steps
#pragma unroll
    for (int c = 0; c < 4; ++c) {
      const int idx = c * 4 + wv;
      const int tr = idx * 8 + s_row;
      gload16(cb + (size_t)(m0 + tr) * INTER + k0 + s_col, &As[idx * 512]);
      gload16(wd + (size_t)(n0 + tr) * INTER + k0 + s_col, &Bs[idx * 512]);
    }
    __syncthreads();
#pragma unroll
    for (int kk = 0; kk < 2; ++kk) {
      const int ko = kk * 32 + (lane >> 4) * 8;
      bf16x8 af[4], bf[4];
#pragma unroll
      for (int m = 0; m < 4; ++m) {
        const int row = wr * 64 + m * 16 + (lane & 15);
        af[m] = *reinterpret_cast<const bf16x8*>(&As[row * BK + ko]);
      }
#pragma unroll
      for (int n = 0; n < 4; ++n) {
        const int row = wc * 64 + n * 16 + (lane & 15);
        bf[n] = *reinterpret_cast<const bf16x8*>(&Bs[row * BK + ko]);
      }
#pragma unroll
      for (int m = 0; m < 4; ++m)
#pragma unroll
        for (int n = 0; n < 4; ++n)
          acc[m][n] = __builtin_amdgcn_mfma_f32_16x16x32_bf16(af[m], bf[n], acc[m][n], 0, 0, 0);
    }
    __syncthreads();
  }

  const int cc = lane & 15;
  const int jj0 = (lane >> 4) * 4;
#pragma unroll
  for (int m = 0; m < 4; ++m)
#pragma unroll
    for (int n = 0; n < 4; ++n)
#pragma unroll
      for (int r = 0; r < 4; ++r)
        out[(size_t)(m0 + wr * 64 + m * 16 + jj0 + r) * HIDDEN +
            n0 + wc * 64 + n * 16 + cc] = acc[m][n][r];
}

// ---------------------------------------------------------------------------
// Launch: converts -> fused GEMM1 -> GEMM2.  Workspace layout (bf16 elems):
//   xb  [4096*2048]   16.78 MB
//   wgb [5504*2048]   22.54 MB
//   wub [5504*2048]   22.54 MB
//   wdb [5504*2048]   22.54 MB   (w_down is 2048x5504, same elem count)
//   cb  [4096*5504]   45.09 MB
// total ~123.5 MiB.  If ws_size is smaller we early-return (output stays
// poisoned -> absmax failure tells us it was the workspace, not a fault).
// ---------------------------------------------------------------------------
extern "C" void kernel_launch(void* const* d_in, const int* in_sizes, int n_in,
                              void* d_out, int out_size, void* d_ws, size_t ws_size,
                              hipStream_t stream) {
  (void)in_sizes; (void)n_in; (void)out_size;
  const size_t need_elems = (size_t)MROWS * HIDDEN + 3 * (size_t)INTER * HIDDEN +
                            (size_t)MROWS * INTER;
  if (ws_size < need_elems * sizeof(unsigned short)) return;  // diagnostic guard

  const float* x = (const float*)d_in[0];
  const float* w_gate = (const float*)d_in[1];
  const float* w_up = (const float*)d_in[2];
  const float* w_down = (const float*)d_in[3];
  float* out = (float*)d_out;

  unsigned short* xb = (unsigned short*)d_ws;
  unsigned short* wgb = xb + (size_t)MROWS * HIDDEN;
  unsigned short* wub = wgb + (size_t)INTER * HIDDEN;
  unsigned short* wdb = wub + (size_t)INTER * HIDDEN;
  unsigned short* cb = wdb + (size_t)INTER * HIDDEN;

  {
    int n4 = MROWS * HIDDEN / 4;
    convert_kernel<<<(n4 + 255) / 256, 256, 0, stream>>>(x, xb, n4);
  }
  {
    int n4 = INTER * HIDDEN / 4;
    convert_kernel<<<(n4 + 255) / 256, 256, 0, stream>>>(w_gate, wgb, n4);
    convert_kernel<<<(n4 + 255) / 256, 256, 0, stream>>>(w_up, wub, n4);
    convert_kernel<<<(n4 + 255) / 256, 256, 0, stream>>>(w_down, wdb, n4);
  }

  gemm1_fused<<<dim3(INTER / 128, BS_ROWS / 32), 256, 0, stream>>>(xb, wgb, wub, cb);
  gemm2_down<<<dim3(HIDDEN / 128, MROWS / 128), 256, 0, stream>>>(cb, wdb, out);
}

// Round 5
// 469.575 us; speedup vs baseline: 1.5019x; 1.5019x over previous
//
#include <hip/hip_runtime.h>
#include <cstdint>
#include <cstddef>

// Problem constants (fixed by the reference)
#define HIDDEN 2048
#define INTER 5504
#define BS_ROWS 1024   // bsz*seq = 2*512
#define MROWS 4096     // T*bsz*seq

typedef short bf16x8 __attribute__((ext_vector_type(8)));   // 8 bf16 in 4 VGPRs
typedef float f32x4 __attribute__((ext_vector_type(4)));

#define WAIT_VMCNT(N) asm volatile("s_waitcnt vmcnt(" #N ")" ::: "memory")

__device__ __forceinline__ void barrier_raw() {
  asm volatile("" ::: "memory");
  __builtin_amdgcn_s_barrier();
  asm volatile("" ::: "memory");
}

__device__ __forceinline__ unsigned short f2bf(float f) {
  unsigned int u = __float_as_uint(f);
  u += 0x7fffu + ((u >> 16) & 1u);   // round-to-nearest-even
  return (unsigned short)(u >> 16);
}

__global__ void convert_kernel(const float* __restrict__ in,
                               unsigned short* __restrict__ out, int n4) {
  int i = blockIdx.x * blockDim.x + threadIdx.x;
  if (i >= n4) return;
  float4 v = reinterpret_cast<const float4*>(in)[i];
  ushort4 o;
  o.x = f2bf(v.x); o.y = f2bf(v.y); o.z = f2bf(v.z); o.w = f2bf(v.w);
  reinterpret_cast<ushort4*>(out)[i] = o;
}

// async global->LDS: lds dst = wave-uniform base + lane*16 (linear);
// global src is per-lane (carries the inverse swizzle).
__device__ __forceinline__ void gload16(const unsigned short* g, unsigned short* lds) {
  __builtin_amdgcn_global_load_lds(
      (const __attribute__((address_space(1))) unsigned int*)g,
      (__attribute__((address_space(3))) unsigned int*)lds, 16, 0, 0);
}

// Swizzle scheme (both GEMMs, BK=64, row = 64 bf16 = 128 B = 8 x 16B slots):
//   LDS[row][c] holds global col  k0 + ((c/8) ^ (row&7))*8 + c%8
//   write side: linear dest; per-lane source col = ((l&7) ^ (l>>3))*8  (row&7 == l>>3)
//   read  side: elem addr = row*64 + (ko ^ ((row&7)*8))  -> 2-way banks (free, m136)

// ---------------------------------------------------------------------------
// GEMM1 (fused): gate/up projections + cumsum/silu/hadamard epilogue.
// 512 thr (8 waves, 4Mx2N), tile 256 rows (64 bs x 4 t) x 128 inter cols, BK=64.
// Tile row i: t=(i>>4)&3, bs=(i>>6)*16+(i&15)  => acc m-index == t (thread-local SNN).
// LDS 128 KB: A[2][256x64] + G[2][128x64] + U[2][128x64], depth-2 counted-vmcnt pipe.
// ---------------------------------------------------------------------------
__global__ __launch_bounds__(512, 2) void gemm1_fused(
    const unsigned short* __restrict__ xb,   // 4096 x 2048
    const unsigned short* __restrict__ wg,   // 5504 x 2048
    const unsigned short* __restrict__ wu,   // 5504 x 2048
    unsigned short* __restrict__ cb) {       // 4096 x 5504
  extern __shared__ unsigned short smem[];
  unsigned short* Abuf = smem;                      // 2 * 16384
  unsigned short* Gbuf = smem + 2 * 16384;          // 2 * 8192
  unsigned short* Ubuf = smem + 2 * 16384 + 2 * 8192;

  const int tid = threadIdx.x;
  const int lane = tid & 63;
  const int wv = tid >> 6;    // 0..7
  const int wr = wv >> 1;     // 0..3 (M)
  const int wc = wv & 1;      // 0..1 (N)

  // T1: bijective XCD swizzle, y-fast (B-panel reuse per XCD). 688 = 8*86.
  const int lin = blockIdx.x * 16 + blockIdx.y;
  const int swz = (lin & 7) * 86 + (lin >> 3);
  const int bx = swz / 16, by = swz % 16;
  const int r0 = by * 64;     // bs-row base
  const int n0 = bx * 128;    // inter col base

  const int l3 = lane >> 3;                         // 0..7
  const int sslot = (((lane & 7) ^ l3) * 8);        // inverse-swizzled src col

  f32x4 accg[4][4], accu[4][4];
#pragma unroll
  for (int m = 0; m < 4; ++m)
#pragma unroll
    for (int n = 0; n < 4; ++n) {
      accg[m][n] = f32x4{0.f, 0.f, 0.f, 0.f};
      accu[m][n] = f32x4{0.f, 0.f, 0.f, 0.f};
    }

  auto STAGE = [&](int k0, int b) {   // 8 gload16 issues per wave per tile
    unsigned short* Ad = Abuf + b * 16384;
    unsigned short* Gd = Gbuf + b * 8192;
    unsigned short* Ud = Ubuf + b * 8192;
#pragma unroll
    for (int c = 0; c < 4; ++c) {
      const int idx = c * 8 + wv;            // 0..31 (wave-uniform)
      const int row = idx * 8 + l3;          // 0..255
      const int t = (row >> 4) & 3;
      const int grow = t * BS_ROWS + r0 + (row >> 6) * 16 + (row & 15);
      gload16(xb + (size_t)grow * HIDDEN + k0 + sslot, Ad + idx * 512);
    }
#pragma unroll
    for (int c = 0; c < 2; ++c) {
      const int idx = c * 8 + wv;            // 0..15
      const int row = idx * 8 + l3;          // 0..127
      gload16(wg + (size_t)(n0 + row) * HIDDEN + k0 + sslot, Gd + idx * 512);
      gload16(wu + (size_t)(n0 + row) * HIDDEN + k0 + sslot, Ud + idx * 512);
    }
  };

  const int NT = HIDDEN / 64;   // 32
  STAGE(0, 0);
  STAGE(64, 1);

  const int m15 = lane & 15;
  const int kbase = (lane >> 4) * 8;     // 0,8,16,24
  const int rsw = (lane & 7) * 8;        // (row&7)*8 read-swizzle term
  int cur = 0;

  for (int t = 0; t < NT; ++t) {
    if (t + 1 < NT) { WAIT_VMCNT(8); } else { WAIT_VMCNT(0); }
    barrier_raw();   // tile t fully staged, all waves
    const unsigned short* Ar = Abuf + cur * 16384;
    const unsigned short* Gr = Gbuf + cur * 8192;
    const unsigned short* Ur = Ubuf + cur * 8192;
#pragma unroll
    for (int kk = 0; kk < 2; ++kk) {
      const int col = (kk * 32 + kbase) ^ rsw;
      bf16x8 af[4], bgf[4], buf[4];
#pragma unroll
      for (int m = 0; m < 4; ++m)
        af[m] = *reinterpret_cast<const bf16x8*>(Ar + (wr * 64 + m * 16 + m15) * 64 + col);
#pragma unroll
      for (int n = 0; n < 4; ++n) {
        const int row = wc * 64 + n * 16 + m15;
        bgf[n] = *reinterpret_cast<const bf16x8*>(Gr + row * 64 + col);
        buf[n] = *reinterpret_cast<const bf16x8*>(Ur + row * 64 + col);
      }
      __builtin_amdgcn_s_setprio(1);
#pragma unroll
      for (int m = 0; m < 4; ++m)
#pragma unroll
        for (int n = 0; n < 4; ++n) {
          accg[m][n] = __builtin_amdgcn_mfma_f32_16x16x32_bf16(af[m], bgf[n], accg[m][n], 0, 0, 0);
          accu[m][n] = __builtin_amdgcn_mfma_f32_16x16x32_bf16(af[m], buf[n], accu[m][n], 0, 0, 0);
        }
      __builtin_amdgcn_s_setprio(0);
    }
    barrier_raw();   // all waves done reading buf[cur]
    if (t + 2 < NT) STAGE((t + 2) * 64, cur);   // refill just-freed buffer
    cur ^= 1;
  }

  // Epilogue: Y_t = silu(cumsum g), A_t = Y_t - Y_{t-1}, SA=Y_3, SB=sum(u),
  // C_t = 0.5*(A_t*SB + u_t*SA)
  const int cc = lane & 15;
  const int jj0 = (lane >> 4) * 4;
#pragma unroll
  for (int n = 0; n < 4; ++n) {
    const int col = n0 + wc * 64 + n * 16 + cc;
#pragma unroll
    for (int r = 0; r < 4; ++r) {
      const int row_bs = r0 + wr * 16 + jj0 + r;
      const float g0 = accg[0][n][r], g1 = accg[1][n][r];
      const float g2 = accg[2][n][r], g3 = accg[3][n][r];
      const float u0 = accu[0][n][r], u1 = accu[1][n][r];
      const float u2 = accu[2][n][r], u3 = accu[3][n][r];
      float xx = g0;
      const float y0 = xx / (1.f + __expf(-xx));
      xx += g1;
      const float y1 = xx / (1.f + __expf(-xx));
      xx += g2;
      const float y2 = xx / (1.f + __expf(-xx));
      xx += g3;
      const float y3 = xx / (1.f + __expf(-xx));
      const float sa = y3;
      const float sb = u0 + u1 + u2 + u3;
      const size_t base = (size_t)row_bs * INTER + col;
      const size_t ts = (size_t)BS_ROWS * INTER;
      cb[base]          = f2bf(0.5f * (y0 * sb + u0 * sa));
      cb[base + ts]     = f2bf(0.5f * ((y1 - y0) * sb + u1 * sa));
      cb[base + 2 * ts] = f2bf(0.5f * ((y2 - y1) * sb + u2 * sa));
      cb[base + 3 * ts] = f2bf(0.5f * ((y3 - y2) * sb + u3 * sa));
    }
  }
}

// ---------------------------------------------------------------------------
// GEMM2: down = C @ w_down^T. 512 thr, tile 256x128, BK=64, same pipe/swizzle.
// LDS 96 KB: A[2][256x64] + B[2][128x64]. Grid 16x16 = 256 blocks = 1/CU.
// ---------------------------------------------------------------------------
__global__ __launch_bounds__(512, 2) void gemm2_down(
    const unsigned short* __restrict__ cb,   // 4096 x 5504
    const unsigned short* __restrict__ wd,   // 2048 x 5504
    float* __restrict__ out) {               // 4096 x 2048 f32
  extern __shared__ unsigned short smem[];
  unsigned short* Abuf = smem;                 // 2 * 16384
  unsigned short* Bbuf = smem + 2 * 16384;     // 2 * 8192

  const int tid = threadIdx.x;
  const int lane = tid & 63;
  const int wv = tid >> 6;
  const int wr = wv >> 1;     // 0..3
  const int wc = wv & 1;      // 0..1

  const int lin = blockIdx.x * 16 + blockIdx.y;   // grid (16,16), 256 = 8*32
  const int swz = (lin & 7) * 32 + (lin >> 3);
  const int bx = swz / 16, by = swz % 16;
  const int m0 = by * 256;
  const int n0 = bx * 128;

  const int l3 = lane >> 3;
  const int sslot = (((lane & 7) ^ l3) * 8);

  f32x4 acc[4][4];
#pragma unroll
  for (int m = 0; m < 4; ++m)
#pragma unroll
    for (int n = 0; n < 4; ++n) acc[m][n] = f32x4{0.f, 0.f, 0.f, 0.f};

  auto STAGE = [&](int k0, int b) {   // 6 issues per wave per tile
    unsigned short* Ad = Abuf + b * 16384;
    unsigned short* Bd = Bbuf + b * 8192;
#pragma unroll
    for (int c = 0; c < 4; ++c) {
      const int idx = c * 8 + wv;
      const int row = idx * 8 + l3;          // 0..255
      gload16(cb + (size_t)(m0 + row) * INTER + k0 + sslot, Ad + idx * 512);
    }
#pragma unroll
    for (int c = 0; c < 2; ++c) {
      const int idx = c * 8 + wv;
      const int row = idx * 8 + l3;          // 0..127
      gload16(wd + (size_t)(n0 + row) * INTER + k0 + sslot, Bd + idx * 512);
    }
  };

  const int NT = INTER / 64;   // 86
  STAGE(0, 0);
  STAGE(64, 1);

  const int m15 = lane & 15;
  const int kbase = (lane >> 4) * 8;
  const int rsw = (lane & 7) * 8;
  int cur = 0;

  for (int t = 0; t < NT; ++t) {
    if (t + 1 < NT) { WAIT_VMCNT(6); } else { WAIT_VMCNT(0); }
    barrier_raw();
    const unsigned short* Ar = Abuf + cur * 16384;
    const unsigned short* Br = Bbuf + cur * 8192;
#pragma unroll
    for (int kk = 0; kk < 2; ++kk) {
      const int col = (kk * 32 + kbase) ^ rsw;
      bf16x8 af[4], bf[4];
#pragma unroll
      for (int m = 0; m < 4; ++m)
        af[m] = *reinterpret_cast<const bf16x8*>(Ar + (wr * 64 + m * 16 + m15) * 64 + col);
#pragma unroll
      for (int n = 0; n < 4; ++n)
        bf[n] = *reinterpret_cast<const bf16x8*>(Br + (wc * 64 + n * 16 + m15) * 64 + col);
      __builtin_amdgcn_s_setprio(1);
#pragma unroll
      for (int m = 0; m < 4; ++m)
#pragma unroll
        for (int n = 0; n < 4; ++n)
          acc[m][n] = __builtin_amdgcn_mfma_f32_16x16x32_bf16(af[m], bf[n], acc[m][n], 0, 0, 0);
      __builtin_amdgcn_s_setprio(0);
    }
    barrier_raw();
    if (t + 2 < NT) STAGE((t + 2) * 64, cur);
    cur ^= 1;
  }

  const int cc = lane & 15;
  const int jj0 = (lane >> 4) * 4;
#pragma unroll
  for (int m = 0; m < 4; ++m)
#pragma unroll
    for (int n = 0; n < 4; ++n)
#pragma unroll
      for (int r = 0; r < 4; ++r)
        out[(size_t)(m0 + wr * 64 + m * 16 + jj0 + r) * HIDDEN +
            n0 + wc * 64 + n * 16 + cc] = acc[m][n][r];
}

// ---------------------------------------------------------------------------
// Launch: converts -> fused GEMM1 -> GEMM2. Workspace (bf16): xb, wgb, wub,
// wdb, cb  = ~123.5 MiB. Guard early-returns if ws too small (diagnostic).
// ---------------------------------------------------------------------------
extern "C" void kernel_launch(void* const* d_in, const int* in_sizes, int n_in,
                              void* d_out, int out_size, void* d_ws, size_t ws_size,
                              hipStream_t stream) {
  (void)in_sizes; (void)n_in; (void)out_size;
  const size_t need_elems = (size_t)MROWS * HIDDEN + 3 * (size_t)INTER * HIDDEN +
                            (size_t)MROWS * INTER;
  if (ws_size < need_elems * sizeof(unsigned short)) return;  // diagnostic guard

  const float* x = (const float*)d_in[0];
  const float* w_gate = (const float*)d_in[1];
  const float* w_up = (const float*)d_in[2];
  const float* w_down = (const float*)d_in[3];
  float* out = (float*)d_out;

  unsigned short* xb = (unsigned short*)d_ws;
  unsigned short* wgb = xb + (size_t)MROWS * HIDDEN;
  unsigned short* wub = wgb + (size_t)INTER * HIDDEN;
  unsigned short* wdb = wub + (size_t)INTER * HIDDEN;
  unsigned short* cb = wdb + (size_t)INTER * HIDDEN;

  // allow >64KB dynamic LDS (idempotent; host-side, graph-capture safe)
  (void)hipFuncSetAttribute(reinterpret_cast<const void*>(gemm1_fused),
                            hipFuncAttributeMaxDynamicSharedMemorySize, 131072);
  (void)hipFuncSetAttribute(reinterpret_cast<const void*>(gemm2_down),
                            hipFuncAttributeMaxDynamicSharedMemorySize, 98304);

  {
    int n4 = MROWS * HIDDEN / 4;
    convert_kernel<<<(n4 + 255) / 256, 256, 0, stream>>>(x, xb, n4);
  }
  {
    int n4 = INTER * HIDDEN / 4;
    convert_kernel<<<(n4 + 255) / 256, 256, 0, stream>>>(w_gate, wgb, n4);
    convert_kernel<<<(n4 + 255) / 256, 256, 0, stream>>>(w_up, wub, n4);
    convert_kernel<<<(n4 + 255) / 256, 256, 0, stream>>>(w_down, wdb, n4);
  }

  gemm1_fused<<<dim3(INTER / 128, BS_ROWS / 64), 512, 131072, stream>>>(xb, wgb, wub, cb);
  gemm2_down<<<dim3(HIDDEN / 128, MROWS / 256), 512, 98304, stream>>>(cb, wdb, out);
}